// Round 4
// baseline (166.638 us; speedup 1.0000x reference)
//
#include <hip/hip_runtime.h>

#define IMG_H 896
#define IMG_W 1344
#define NPIX (IMG_H * IMG_W)   // 1,204,224 = 4704 * 256 exactly

// Fused per-pixel MLP 6->32->32->3 + relu, ONE pixel per thread.
// Key structural choice: layer1 and layer2 are interleaved per hidden
// channel c, so the live set is {xi[6], h2[32], h1c} ~= 46 VGPRs. This fits
// the compiler's occupancy-driven register budget WITHOUT restructuring /
// recomputation (R1's VGPR=36 build re-executed ~2x the ideal op count).
// Ideal stream: ~1450 VALU ops/px -> 21.8 us at 100% VALU issue.
__global__ __launch_bounds__(256, 4) void mlp_pixel_kernel(
    const float* __restrict__ x,
    const float* __restrict__ w1, const float* __restrict__ b1,
    const float* __restrict__ w2, const float* __restrict__ b2,
    const float* __restrict__ w3, const float* __restrict__ b3,
    float* __restrict__ out)
{
    int p = blockIdx.x * 256 + threadIdx.x;
    if (p >= NPIX) return;

    // 6 input channels, 24 B/pixel, 8-B aligned -> 3x float2
    const float2* xp = reinterpret_cast<const float2*>(x + (size_t)p * 6);
    float2 x01 = xp[0];
    float2 x23 = xp[1];
    float2 x45 = xp[2];
    float xi0 = x01.x, xi1 = x01.y, xi2 = x23.x,
          xi3 = x23.y, xi4 = x45.x, xi5 = x45.y;

    // layer-2 accumulators, init with bias
    float h2[32];
#pragma unroll
    for (int d = 0; d < 32; ++d) h2[d] = b2[d];

    // interleaved layer1+layer2: per hidden channel c
#pragma unroll
    for (int c = 0; c < 32; ++c) {
        float h = b1[c];
        h = fmaf(xi0, w1[0 * 32 + c], h);
        h = fmaf(xi1, w1[1 * 32 + c], h);
        h = fmaf(xi2, w1[2 * 32 + c], h);
        h = fmaf(xi3, w1[3 * 32 + c], h);
        h = fmaf(xi4, w1[4 * 32 + c], h);
        h = fmaf(xi5, w1[5 * 32 + c], h);
        h = fmaxf(h, 0.0f);
#pragma unroll
        for (int d = 0; d < 32; ++d)
            h2[d] = fmaf(h, w2[c * 32 + d], h2[d]);
    }

    // layer 3: 32 -> 3 (relu on h2 applied once, in place)
    float o0 = b3[0], o1 = b3[1], o2 = b3[2];
#pragma unroll
    for (int c = 0; c < 32; ++c) {
        float h = fmaxf(h2[c], 0.0f);
        o0 = fmaf(h, w3[c * 3 + 0], o0);
        o1 = fmaf(h, w3[c * 3 + 1], o1);
        o2 = fmaf(h, w3[c * 3 + 2], o2);
    }
    o0 = fmaxf(o0, 0.0f);
    o1 = fmaxf(o1, 0.0f);
    o2 = fmaxf(o2, 0.0f);

    float* op = out + (size_t)p * 3;
    op[0] = o0;
    op[1] = o1;
    op[2] = o2;
}

extern "C" void kernel_launch(void* const* d_in, const int* in_sizes, int n_in,
                              void* d_out, int out_size, void* d_ws, size_t ws_size,
                              hipStream_t stream) {
    const float* x  = (const float*)d_in[0];
    const float* w1 = (const float*)d_in[1];
    const float* b1 = (const float*)d_in[2];
    const float* w2 = (const float*)d_in[3];
    const float* b2 = (const float*)d_in[4];
    const float* w3 = (const float*)d_in[5];
    const float* b3 = (const float*)d_in[6];
    float* out = (float*)d_out;

    int grid = NPIX / 256;  // 4704 exactly
    mlp_pixel_kernel<<<grid, 256, 0, stream>>>(x, w1, b1, w2, b2, w3, b3, out);
}

// Round 8
// 97.103 us; speedup vs baseline: 1.7161x; 1.7161x over previous
//
#include <hip/hip_runtime.h>

typedef _Float16 f16x8 __attribute__((ext_vector_type(8)));
typedef float    f32x16 __attribute__((ext_vector_type(16)));

#define NPIX (896*1344)          // 1,204,224
#define TPW   8                  // 32-px tiles per wave
#define WPB   4                  // waves per block
#define NBLK  (NPIX / (32*TPW*WPB))   // 1176 exactly

__device__ __forceinline__ unsigned pk2(float a, float b) {
    auto h = __builtin_amdgcn_cvt_pkrtz(a, b);   // __fp16 ext_vector_type(2)
    return __builtin_bit_cast(unsigned, h);
}

// Per-32px-tile MLP via v_mfma_f32_32x32x16_f16, swapped-operand form:
//   C[ch_out][px] = sum_k W[k][ch_out] * act[px][k]
// A-frags (weights) hoisted per wave; B-frags from x / LDS transpose.
// k-slot mapping k = 16f + 8h + j used consistently for A and B (slot-wise
// pairing makes any true hw slot permutation cancel). C/D layout (m101):
//   col = lane&31 (px), row = (r&3) + 8*(r>>2) + 4*(lane>>5) (ch).
// LDS transpose swizzle: unit' = unit ^ ((m>>1)&3). Bank base is
// 16*(m&1) + 4*unit' + 2h; (m>>1)&3 cycles 0..3 within each parity class,
// so write (b64) and read (b128) are both exactly minimum-phase (0 conflict).
__global__ __launch_bounds__(256) void mlp_mfma_kernel(
    const float* __restrict__ x,
    const float* __restrict__ w1, const float* __restrict__ b1,
    const float* __restrict__ w2, const float* __restrict__ b2,
    const float* __restrict__ w3, const float* __restrict__ b3,
    float* __restrict__ out)
{
    __shared__ __align__(16) unsigned lds1[WPB][512];  // 2KB/wave h1 [px][ch] f16
    __shared__ __align__(16) unsigned lds2[WPB][512];  // 2KB/wave h2

    const int lane = threadIdx.x & 63;
    const int wv   = threadIdx.x >> 6;
    const int m    = lane & 31;   // A row (ch_out) / B col (px)
    const int h    = lane >> 5;
    const int gw   = blockIdx.x * WPB + wv;
    const int swz  = (m >> 1) & 3;   // conflict-free 16B-unit XOR swizzle

    // ---- hoisted A fragments (addresses clamped in-bounds before select) ----
    f16x8 a1, a2f0, a2f1, a3f0, a3f1;
#pragma unroll
    for (int j = 0; j < 8; ++j) {
        int k = 8*h + j;
        float v = w1[(k < 6 ? k : 0)*32 + m];          // w1: [6][32]
        a1[j] = (k < 6) ? (_Float16)v : (_Float16)0.0f;
    }
#pragma unroll
    for (int j = 0; j < 8; ++j) a2f0[j] = (_Float16)w2[(8*h + j)*32 + m];        // w2: [32][32]
#pragma unroll
    for (int j = 0; j < 8; ++j) a2f1[j] = (_Float16)w2[(16 + 8*h + j)*32 + m];
    const int mc = (m < 3) ? m : 0;
#pragma unroll
    for (int j = 0; j < 8; ++j) {
        float v0 = w3[(8*h + j)*3 + mc];               // w3: [32][3]
        float v1 = w3[(16 + 8*h + j)*3 + mc];
        a3f0[j] = (m < 3) ? (_Float16)v0 : (_Float16)0.0f;
        a3f1[j] = (m < 3) ? (_Float16)v1 : (_Float16)0.0f;
    }

    // ---- bias C-in fragments: row(r) = (r&3)+8*(r>>2)+4h ----
    f32x16 bias1, bias2;
#pragma unroll
    for (int r = 0; r < 16; ++r) {
        int row = (r & 3) + 8*(r >> 2) + 4*h;
        bias1[r] = b1[row];
        bias2[r] = b2[row];
    }
    const float b3v0 = b3[0], b3v1 = b3[1], b3v2 = b3[2];

    for (int t = 0; t < TPW; ++t) {
        const int p = gw*(TPW*32) + t*32 + m;   // this lane's pixel (px = m)

        // ---- B1 = x fragment: slot j holds x[p][8h+j], zeros for k>=6 ----
        union { f16x8 v; unsigned u[4]; } bx = {};
        if (h == 0) {
            const float2* xp = (const float2*)(x + (size_t)p*6);
            float2 x01 = xp[0], x23 = xp[1], x45 = xp[2];
            bx.u[0] = pk2(x01.x, x01.y);
            bx.u[1] = pk2(x23.x, x23.y);
            bx.u[2] = pk2(x45.x, x45.y);   // u[3] stays 0 (k=6,7 pad)
        }

        // ---- layer 1 (bias via C-in), relu, pack, transposed LDS write ----
        f32x16 acc = __builtin_amdgcn_mfma_f32_32x32x16_f16(a1, bx.v, bias1, 0, 0, 0);
#pragma unroll
        for (int w = 0; w < 4; ++w) {   // write w: ch {8w+4h .. +3} at unit w
            unsigned lo = pk2(fmaxf(acc[4*w+0],0.f), fmaxf(acc[4*w+1],0.f));
            unsigned hi = pk2(fmaxf(acc[4*w+2],0.f), fmaxf(acc[4*w+3],0.f));
            int dw = m*16 + 4*(w ^ swz) + 2*h;
            uint2 val; val.x = lo; val.y = hi;
            *(uint2*)&lds1[wv][dw] = val;
        }
        asm volatile("s_waitcnt lgkmcnt(0)" ::: "memory");
        __builtin_amdgcn_sched_barrier(0);

        // ---- B2 frags: slot j = h1[px][16f+8h+j] (unit u = 2f+h) ----
        union { uint4 q; f16x8 v; } bh10, bh11;
        bh10.q = *(const uint4*)&lds1[wv][m*16 + 4*((0 + h) ^ swz)];
        bh11.q = *(const uint4*)&lds1[wv][m*16 + 4*((2 + h) ^ swz)];

        acc = __builtin_amdgcn_mfma_f32_32x32x16_f16(a2f0, bh10.v, bias2, 0, 0, 0);
        acc = __builtin_amdgcn_mfma_f32_32x32x16_f16(a2f1, bh11.v, acc,   0, 0, 0);

#pragma unroll
        for (int w = 0; w < 4; ++w) {
            unsigned lo = pk2(fmaxf(acc[4*w+0],0.f), fmaxf(acc[4*w+1],0.f));
            unsigned hi = pk2(fmaxf(acc[4*w+2],0.f), fmaxf(acc[4*w+3],0.f));
            int dw = m*16 + 4*(w ^ swz) + 2*h;
            uint2 val; val.x = lo; val.y = hi;
            *(uint2*)&lds2[wv][dw] = val;
        }
        asm volatile("s_waitcnt lgkmcnt(0)" ::: "memory");
        __builtin_amdgcn_sched_barrier(0);

        union { uint4 q; f16x8 v; } bh20, bh21;
        bh20.q = *(const uint4*)&lds2[wv][m*16 + 4*((0 + h) ^ swz)];
        bh21.q = *(const uint4*)&lds2[wv][m*16 + 4*((2 + h) ^ swz)];

        f32x16 accz;
#pragma unroll
        for (int r = 0; r < 16; ++r) accz[r] = 0.0f;
        accz = __builtin_amdgcn_mfma_f32_32x32x16_f16(a3f0, bh20.v, accz, 0, 0, 0);
        accz = __builtin_amdgcn_mfma_f32_32x32x16_f16(a3f1, bh21.v, accz, 0, 0, 0);

        // rows 0..2 (= out ch 0..2) live in lanes 0..31, regs r=0..2
        if (h == 0) {
            float* op = out + (size_t)p*3;
            op[0] = fmaxf(accz[0] + b3v0, 0.f);
            op[1] = fmaxf(accz[1] + b3v1, 0.f);
            op[2] = fmaxf(accz[2] + b3v2, 0.f);
        }
    }
}

extern "C" void kernel_launch(void* const* d_in, const int* in_sizes, int n_in,
                              void* d_out, int out_size, void* d_ws, size_t ws_size,
                              hipStream_t stream) {
    const float* x  = (const float*)d_in[0];
    const float* w1 = (const float*)d_in[1];
    const float* b1 = (const float*)d_in[2];
    const float* w2 = (const float*)d_in[3];
    const float* b2 = (const float*)d_in[4];
    const float* w3 = (const float*)d_in[5];
    const float* b3 = (const float*)d_in[6];
    float* out = (float*)d_out;

    mlp_mfma_kernel<<<NBLK, 256, 0, stream>>>(x, w1, b1, w2, b2, w3, b3, out);
}

// Round 10
// 97.057 us; speedup vs baseline: 1.7169x; 1.0005x over previous
//
#include <hip/hip_runtime.h>

typedef _Float16 f16x8 __attribute__((ext_vector_type(8)));
typedef float    f32x16 __attribute__((ext_vector_type(16)));

#define NPIX (896*1344)          // 1,204,224
#define TPW   4                  // 32-px tiles per wave
#define WPB   4                  // waves per block (256 threads)
#define NBLK  (NPIX / (32*TPW*WPB))   // 2352 exactly

__device__ __forceinline__ unsigned pk2(float a, float b) {
    auto h = __builtin_amdgcn_cvt_pkrtz(a, b);   // __fp16 ext_vector_type(2)
    return __builtin_bit_cast(unsigned, h);
}

// relu(acc) -> f16 pairs -> permlane32_swap half-exchange -> B-frags of the
// next layer. Derivation (C/D: lane(m,h) holds ch (r&3)+8*(r>>2)+4h; B needs
// slot j = ch {8h+j} (fr0) and {16+8h+j} (fr1)):
//   swap(a,b): r[0] = [a_lo | b_lo], r[1] = [a_hi | b_hi]   (lo = lanes 0..31)
//   fr0 = [r0[0], r1[0], r0[1], r1[1]] with r0=swap(A0,B0), r1=swap(A1,B1)
//   (h=0: ch 0,1|2,3|4,5|6,7 ; h=1: ch 8,9|10,11|12,13|14,15)  -- exact match.
__device__ __forceinline__ void pack_swap(const f32x16& acc, f16x8& fr0, f16x8& fr1) {
    unsigned A0 = pk2(fmaxf(acc[ 0],0.f), fmaxf(acc[ 1],0.f));
    unsigned A1 = pk2(fmaxf(acc[ 2],0.f), fmaxf(acc[ 3],0.f));
    unsigned B0 = pk2(fmaxf(acc[ 4],0.f), fmaxf(acc[ 5],0.f));
    unsigned B1 = pk2(fmaxf(acc[ 6],0.f), fmaxf(acc[ 7],0.f));
    unsigned C0 = pk2(fmaxf(acc[ 8],0.f), fmaxf(acc[ 9],0.f));
    unsigned C1 = pk2(fmaxf(acc[10],0.f), fmaxf(acc[11],0.f));
    unsigned D0 = pk2(fmaxf(acc[12],0.f), fmaxf(acc[13],0.f));
    unsigned D1 = pk2(fmaxf(acc[14],0.f), fmaxf(acc[15],0.f));
    auto r0 = __builtin_amdgcn_permlane32_swap(A0, B0, false, false);
    auto r1 = __builtin_amdgcn_permlane32_swap(A1, B1, false, false);
    auto r2 = __builtin_amdgcn_permlane32_swap(C0, D0, false, false);
    auto r3 = __builtin_amdgcn_permlane32_swap(C1, D1, false, false);
    union { unsigned u[4]; f16x8 v; } u0, u1;
    u0.u[0] = r0[0]; u0.u[1] = r1[0]; u0.u[2] = r0[1]; u0.u[3] = r1[1];
    u1.u[0] = r2[0]; u1.u[1] = r3[0]; u1.u[2] = r2[1]; u1.u[3] = r3[1];
    fr0 = u0.v; fr1 = u1.v;
}

// Fully in-register per-32px-tile MLP via v_mfma_f32_32x32x16_f16, swapped
// operands: C[ch_out][px] = sum_k W[k][ch_out]*act[px][k]. No LDS, no fences
// -> compiler pipelines x loads across tiles (plus explicit t+1 prefetch).
// A/B k-slot mapping k = 8h+j (+16 for frag1) used consistently both sides;
// C/D layout col=lane&31 (px), row=(r&3)+8*(r>>2)+4h (HW-validated by R8).
__global__ __launch_bounds__(256) void mlp_mfma_kernel(
    const float* __restrict__ x,
    const float* __restrict__ w1, const float* __restrict__ b1,
    const float* __restrict__ w2, const float* __restrict__ b2,
    const float* __restrict__ w3, const float* __restrict__ b3,
    float* __restrict__ out)
{
    const int lane = threadIdx.x & 63;
    const int wv   = threadIdx.x >> 6;
    const int m    = lane & 31;   // A row (ch_out) / B col (px)
    const int h    = lane >> 5;
    const int gw   = blockIdx.x * WPB + wv;

    // ---- hoisted A fragments ----
    f16x8 a1, a2f0, a2f1, a3f0, a3f1;
#pragma unroll
    for (int j = 0; j < 8; ++j) {
        int k = 8*h + j;
        float v = w1[(k < 6 ? k : 0)*32 + m];          // w1: [6][32]
        a1[j] = (k < 6) ? (_Float16)v : (_Float16)0.0f;
    }
#pragma unroll
    for (int j = 0; j < 8; ++j) a2f0[j] = (_Float16)w2[(8*h + j)*32 + m];        // w2: [32][32]
#pragma unroll
    for (int j = 0; j < 8; ++j) a2f1[j] = (_Float16)w2[(16 + 8*h + j)*32 + m];
    const int mc = (m < 3) ? m : 0;
#pragma unroll
    for (int j = 0; j < 8; ++j) {
        float v0 = w3[(8*h + j)*3 + mc];               // w3: [32][3]
        float v1 = w3[(16 + 8*h + j)*3 + mc];
        a3f0[j] = (m < 3) ? (_Float16)v0 : (_Float16)0.0f;
        a3f1[j] = (m < 3) ? (_Float16)v1 : (_Float16)0.0f;
    }

    // ---- bias C-in fragments: row(r) = (r&3)+8*(r>>2)+4h ----
    f32x16 bias1, bias2, bias3;
#pragma unroll
    for (int r = 0; r < 16; ++r) {
        int row = (r & 3) + 8*(r >> 2) + 4*h;
        bias1[r] = b1[row];
        bias2[r] = b2[row];
        bias3[r] = (h == 0 && r < 3) ? b3[r] : 0.0f;   // out ch r lives at row r, h=0
    }

    // this lane's x pointer (lanes h==0 carry pixels; h==1 contribute zeros)
    const float2* xbase = (const float2*)(x + (size_t)(gw*(TPW*32) + m) * 6);
    float2 nx0, nx1, nx2;
    if (h == 0) { nx0 = xbase[0]; nx1 = xbase[1]; nx2 = xbase[2]; }

    for (int t = 0; t < TPW; ++t) {
        const int p = gw*(TPW*32) + t*32 + m;

        float2 cx0 = nx0, cx1 = nx1, cx2 = nx2;
        if (h == 0 && t + 1 < TPW) {       // prefetch next tile's pixels
            nx0 = xbase[(t+1)*96 + 0];     // 32 px * 6 f32 = 192 f32 = 96 float2
            nx1 = xbase[(t+1)*96 + 1];
            nx2 = xbase[(t+1)*96 + 2];
        }

        // ---- B1 fragment: slot j = x[p][8h+j], zero-padded k>=6 ----
        union { f16x8 v; unsigned u[4]; } bx = {};
        if (h == 0) {
            bx.u[0] = pk2(cx0.x, cx0.y);
            bx.u[1] = pk2(cx1.x, cx1.y);
            bx.u[2] = pk2(cx2.x, cx2.y);   // u[3] stays 0 (k=6,7 pad)
        }

        // ---- layer 1 (bias via C-in) ----
        f32x16 acc = __builtin_amdgcn_mfma_f32_32x32x16_f16(a1, bx.v, bias1, 0, 0, 0);

        // ---- relu+pack+swap -> layer 2 ----
        f16x8 f0, f1;
        pack_swap(acc, f0, f1);
        acc = __builtin_amdgcn_mfma_f32_32x32x16_f16(a2f0, f0, bias2, 0, 0, 0);
        acc = __builtin_amdgcn_mfma_f32_32x32x16_f16(a2f1, f1, acc,   0, 0, 0);

        // ---- relu+pack+swap -> layer 3 (b3 baked into C-in) ----
        pack_swap(acc, f0, f1);
        f32x16 accz = __builtin_amdgcn_mfma_f32_32x32x16_f16(a3f0, f0, bias3, 0, 0, 0);
        accz        = __builtin_amdgcn_mfma_f32_32x32x16_f16(a3f1, f1, accz,  0, 0, 0);

        // out ch 0..2 = rows 0..2 -> regs r=0..2 at h=0 lanes
        if (h == 0) {
            float* op = out + (size_t)p*3;
            op[0] = fmaxf(accz[0], 0.f);
            op[1] = fmaxf(accz[1], 0.f);
            op[2] = fmaxf(accz[2], 0.f);
        }
    }
}

extern "C" void kernel_launch(void* const* d_in, const int* in_sizes, int n_in,
                              void* d_out, int out_size, void* d_ws, size_t ws_size,
                              hipStream_t stream) {
    const float* x  = (const float*)d_in[0];
    const float* w1 = (const float*)d_in[1];
    const float* b1 = (const float*)d_in[2];
    const float* w2 = (const float*)d_in[3];
    const float* b2 = (const float*)d_in[4];
    const float* w3 = (const float*)d_in[5];
    const float* b3 = (const float*)d_in[6];
    float* out = (float*)d_out;

    mlp_mfma_kernel<<<NBLK, 256, 0, stream>>>(x, w1, b1, w2, b2, w3, b3, out);
}